// Round 1
// baseline (638.034 us; speedup 1.0000x reference)
//
#include <hip/hip_runtime.h>
#include <hip/hip_bf16.h>

// Problem: out[b,s,h] = sum_d x[b,s,d] * W[cat[b],d,h] + bias[cat[b],h]
// x: [64,512,1024] f32, cat_ids: [64] int, W: [16,1024,4096] f32, bias: [16,4096] f32
// out: [64,512,4096] f32

#define SEQ 512
#define DIN 1024
#define DH  4096

#define BM 128
#define BN 128
#define BK 64

typedef __attribute__((ext_vector_type(8))) short  short8;   // 8 bf16 = MFMA A/B frag
typedef __attribute__((ext_vector_type(4))) float  f32x4;
typedef __attribute__((ext_vector_type(4))) __bf16 bf16x4;

// XOR swizzle within a 128-byte LDS row: spreads the 16-lane stride-128B
// fragment reads (otherwise all bank 0) across 8 bank groups.
static __device__ __forceinline__ int swz(int row) {
    return ((row ^ (row >> 3)) & 7) << 4;
}

__global__ __launch_bounds__(256, 2)
void cat_lin_mfma(const float* __restrict__ x,
                  const int*   __restrict__ cat_ids,
                  const float* __restrict__ W,
                  const float* __restrict__ bias,
                  float*       __restrict__ out) {
    // A tile: x[mb..mb+127][kt..kt+63] as bf16, row-major [m][k], swizzled
    // B tile: W[kt..kt+63][nb..nb+127] TRANSPOSED to bf16 [n][k], swizzled
    __shared__ unsigned char lA[BM * BK * 2];
    __shared__ unsigned char lB[BN * BK * 2];

    const int t    = threadIdx.x;
    const int lane = t & 63;
    const int wave = t >> 6;
    const int wm   = (wave >> 1) * 64;   // wave's row offset in tile
    const int wn   = (wave & 1) * 64;    // wave's col offset in tile
    const int l15  = lane & 15;
    const int lg   = lane >> 4;

    const int nb = blockIdx.x * BN;
    const int mb = blockIdx.y * BM;
    const int bb = blockIdx.z;
    const int c  = cat_ids[bb];

    const float* xp = x + (size_t)bb * SEQ * DIN + (size_t)mb * DIN;
    const float* wp = W + (size_t)c * DIN * DH + nb;

    f32x4 acc[4][4];
    #pragma unroll
    for (int i = 0; i < 4; i++)
        #pragma unroll
        for (int j = 0; j < 4; j++)
            acc[i][j] = (f32x4)0.f;

    // staging coordinates
    const int aM = t >> 4;            // A: row 0..15 (+16*i), 16 threads/row
    const int aK = (t & 15) * 4;      // A: k offset (float4)
    const int bN = (t & 31) * 4;      // B: col (float4 along n)
    const int bK = (t >> 5) * 4;      // B: k row 0..28 (+32*i)

    for (int kt = 0; kt < DIN; kt += BK) {
        // ---- stage A: coalesced float4 along k, cvt, contiguous b64 write ----
        #pragma unroll
        for (int i = 0; i < 8; i++) {
            const int m = aM + i * 16;
            const f32x4 v = *(const f32x4*)(xp + (size_t)m * DIN + kt + aK);
            bf16x4 h;
            h[0] = (__bf16)v[0]; h[1] = (__bf16)v[1];
            h[2] = (__bf16)v[2]; h[3] = (__bf16)v[3];
            *(bf16x4*)(&lA[m * (BK * 2) + ((aK * 2) ^ swz(m))]) = h;
        }
        // ---- stage B: 4x4 register transpose, b64 writes k-contiguous ----
        #pragma unroll
        for (int i = 0; i < 2; i++) {
            const int k0 = bK + i * 32;
            const float* wrow = wp + (size_t)(kt + k0) * DH + bN;
            const f32x4 r0 = *(const f32x4*)(wrow);
            const f32x4 r1 = *(const f32x4*)(wrow + DH);
            const f32x4 r2 = *(const f32x4*)(wrow + 2 * (size_t)DH);
            const f32x4 r3 = *(const f32x4*)(wrow + 3 * (size_t)DH);
            #pragma unroll
            for (int jj = 0; jj < 4; jj++) {
                bf16x4 h;
                h[0] = (__bf16)r0[jj]; h[1] = (__bf16)r1[jj];
                h[2] = (__bf16)r2[jj]; h[3] = (__bf16)r3[jj];
                const int n = bN + jj;
                *(bf16x4*)(&lB[n * (BK * 2) + ((k0 * 2) ^ swz(n))]) = h;
            }
        }
        __syncthreads();

        // ---- MFMA: 2 k-steps of 32, 4x4 fragments per wave ----
        #pragma unroll
        for (int ks = 0; ks < 2; ks++) {
            const int kb = ks * 64 + lg * 16;   // byte offset of this lane-group's 8 bf16
            short8 af[4], bfr[4];
            #pragma unroll
            for (int f = 0; f < 4; f++) {
                const int m = wm + f * 16 + l15;
                af[f] = *(const short8*)(&lA[m * (BK * 2) + (kb ^ swz(m))]);
                const int n = wn + f * 16 + l15;
                bfr[f] = *(const short8*)(&lB[n * (BK * 2) + (kb ^ swz(n))]);
            }
            #pragma unroll
            for (int fm = 0; fm < 4; fm++)
                #pragma unroll
                for (int fn = 0; fn < 4; fn++)
                    acc[fm][fn] = __builtin_amdgcn_mfma_f32_16x16x32_bf16(
                        af[fm], bfr[fn], acc[fm][fn], 0, 0, 0);
        }
        __syncthreads();
    }

    // ---- epilogue: D[row=(lane>>4)*4+r][col=lane&15] per 16x16 frag ----
    const float* bp = bias + (size_t)c * DH;
    float*       op = out + (size_t)bb * SEQ * DH;
    #pragma unroll
    for (int fn = 0; fn < 4; fn++) {
        const int col = nb + wn + fn * 16 + l15;
        const float bv = bp[col];
        #pragma unroll
        for (int fm = 0; fm < 4; fm++) {
            const int row0 = mb + wm + fm * 16 + lg * 4;
            #pragma unroll
            for (int r = 0; r < 4; r++)
                op[(size_t)(row0 + r) * DH + col] = acc[fm][fn][r] + bv;
        }
    }
}

extern "C" void kernel_launch(void* const* d_in, const int* in_sizes, int n_in,
                              void* d_out, int out_size, void* d_ws, size_t ws_size,
                              hipStream_t stream) {
    const float* x   = (const float*)d_in[0];
    const int*   cid = (const int*)d_in[1];
    const float* W   = (const float*)d_in[2];
    const float* b   = (const float*)d_in[3];
    float*       out = (float*)d_out;

    dim3 grid(DH / BN, SEQ / BM, 64);   // 32 x 4 x 64 = 8192 blocks
    dim3 block(256);
    cat_lin_mfma<<<grid, block, 0, stream>>>(x, cid, W, b, out);
}